// Round 1
// baseline (592.376 us; speedup 1.0000x reference)
//
#include <hip/hip_runtime.h>

#define MB   32      // B*T slices
#define CCH  256     // channels C
#define QCH  32      // q/k channels C/8
#define NPIX 1024    // W*H
#define L2E  1.44269504088896340736f

// workspace layout (in floats)
#define QT_OFF 0
#define KT_OFF (MB * NPIX * QCH)                 // 1048576
#define V_OFF  (2 * MB * NPIX * QCH)             // 2097152
#define A2_OFF (V_OFF + MB * CCH * NPIX)         // 10485760
// total floats = 10518528 -> ~40.1 MB of d_ws

// ---------------------------------------------------------------------------
// K1: projections. out320 = W(320,256) @ X(256,1024) + b, per slice mi.
// Rows 0..31 -> Qt (stored transposed, [n][o]), 32..63 -> Kt ([n][o]),
// 64..319 -> V ([c][n]).  64x64 output tile per block, 4x4 per thread.
// ---------------------------------------------------------------------------
__global__ __launch_bounds__(256) void k_proj(
    const float* __restrict__ x,
    const float* __restrict__ wq, const float* __restrict__ bq,
    const float* __restrict__ wk, const float* __restrict__ bk,
    const float* __restrict__ wv, const float* __restrict__ bv,
    float* __restrict__ ws)
{
    __shared__ float Xs[64][64];   // [c][n], unpadded (float4-aligned rows)
    __shared__ float Ws[64][65];   // [o][c], +1 pad

    const int tid = threadIdx.x;
    const int n0  = blockIdx.x * 64;
    const int o0  = blockIdx.y * 64;
    const int mi  = blockIdx.z;
    const float* xp = x + (size_t)mi * CCH * NPIX;

    const int rg = tid >> 4;   // 0..15 -> o sub-block
    const int jg = tid & 15;   // 0..15 -> n sub-block

    float acc[4][4];
#pragma unroll
    for (int i = 0; i < 4; ++i)
#pragma unroll
        for (int j = 0; j < 4; ++j) acc[i][j] = 0.f;

    for (int c0 = 0; c0 < CCH; c0 += 64) {
        // stage X chunk: X[c0+row][n0 + 4*c4 ...]
#pragma unroll
        for (int r = 0; r < 4; ++r) {
            int idx = tid + r * 256;
            int row = idx >> 4, c4 = idx & 15;
            float4 v = *(const float4*)(xp + (size_t)(c0 + row) * NPIX + n0 + c4 * 4);
            *(float4*)&Xs[row][c4 * 4] = v;
        }
        // stage W chunk (row o0+row of the stacked [wq;wk;wv] matrix)
#pragma unroll
        for (int r = 0; r < 4; ++r) {
            int idx = tid + r * 256;
            int row = idx >> 4, c4 = idx & 15;
            int o = o0 + row;
            const float* wrow = (o < 32) ? (wq + (size_t)o * CCH)
                              : (o < 64) ? (wk + (size_t)(o - 32) * CCH)
                                         : (wv + (size_t)(o - 64) * CCH);
            float4 v = *(const float4*)(wrow + c0 + c4 * 4);
            Ws[row][c4 * 4 + 0] = v.x; Ws[row][c4 * 4 + 1] = v.y;
            Ws[row][c4 * 4 + 2] = v.z; Ws[row][c4 * 4 + 3] = v.w;
        }
        __syncthreads();

#pragma unroll 16
        for (int k = 0; k < 64; ++k) {
            float4 xv = *(const float4*)&Xs[k][jg * 4];
            float wvv[4];
#pragma unroll
            for (int i = 0; i < 4; ++i) wvv[i] = Ws[rg * 4 + i][k];
#pragma unroll
            for (int i = 0; i < 4; ++i) {
                acc[i][0] = fmaf(wvv[i], xv.x, acc[i][0]);
                acc[i][1] = fmaf(wvv[i], xv.y, acc[i][1]);
                acc[i][2] = fmaf(wvv[i], xv.z, acc[i][2]);
                acc[i][3] = fmaf(wvv[i], xv.w, acc[i][3]);
            }
        }
        __syncthreads();
    }

    float* Qt = ws + QT_OFF + (size_t)mi * NPIX * QCH;
    float* Kt = ws + KT_OFF + (size_t)mi * NPIX * QCH;
    float* V  = ws + V_OFF  + (size_t)mi * CCH * NPIX;

    if (o0 == 0) {
        const int obase = rg * 4;      // 0..60
        if (obase < 32) {              // Q rows -> Qt[n][o]
            float b0 = bq[obase], b1 = bq[obase + 1], b2 = bq[obase + 2], b3 = bq[obase + 3];
#pragma unroll
            for (int j = 0; j < 4; ++j) {
                int n = n0 + jg * 4 + j;
                float4 v = { acc[0][j] + b0, acc[1][j] + b1, acc[2][j] + b2, acc[3][j] + b3 };
                *(float4*)(Qt + (size_t)n * QCH + obase) = v;
            }
        } else {                       // K rows -> Kt[n][o]
            int ob = obase - 32;
            float b0 = bk[ob], b1 = bk[ob + 1], b2 = bk[ob + 2], b3 = bk[ob + 3];
#pragma unroll
            for (int j = 0; j < 4; ++j) {
                int n = n0 + jg * 4 + j;
                float4 v = { acc[0][j] + b0, acc[1][j] + b1, acc[2][j] + b2, acc[3][j] + b3 };
                *(float4*)(Kt + (size_t)n * QCH + ob) = v;
            }
        }
    } else {                           // V rows -> V[c][n]
#pragma unroll
        for (int i = 0; i < 4; ++i) {
            int c = o0 - 64 + rg * 4 + i;
            float b = bv[c];
            float4 v = { acc[i][0] + b, acc[i][1] + b, acc[i][2] + b, acc[i][3] + b };
            *(float4*)(V + (size_t)c * NPIX + n0 + jg * 4) = v;
        }
    }
}

// ---------------------------------------------------------------------------
// K2: softmax row stats. Block = 64 energy rows, loops all 1024 cols in
// 64-wide chunks; online (max, sumexp) in exp2 domain; a2[n] = M + log2(S).
// ---------------------------------------------------------------------------
__global__ __launch_bounds__(256) void k_stats(float* __restrict__ ws)
{
    __shared__ float Qs[64][33];
    __shared__ float Ks[64][33];
    __shared__ float Rm[64][17];
    __shared__ float Rs[64][17];

    const int tid = threadIdx.x;
    const int n0  = blockIdx.x * 64;
    const int mi  = blockIdx.y;

    const float* Qt = ws + QT_OFF + (size_t)mi * NPIX * QCH;
    const float* Kt = ws + KT_OFF + (size_t)mi * NPIX * QCH;
    float* a2 = ws + A2_OFF + (size_t)mi * NPIX;

    // stage Q rows n0..n0+63
#pragma unroll
    for (int r = 0; r < 2; ++r) {
        int idx = tid + r * 256;       // 0..511
        int row = idx >> 3, c4 = idx & 7;
        float4 v = *(const float4*)(Qt + (size_t)(n0 + row) * QCH + c4 * 4);
        Qs[row][c4 * 4 + 0] = v.x; Qs[row][c4 * 4 + 1] = v.y;
        Qs[row][c4 * 4 + 2] = v.z; Qs[row][c4 * 4 + 3] = v.w;
    }

    const int rg = tid >> 4, jg = tid & 15;
    float mx[4], sm[4];
#pragma unroll
    for (int rr = 0; rr < 4; ++rr) { mx[rr] = -1e30f; sm[rr] = 0.f; }

    for (int jt = 0; jt < 16; ++jt) {
        __syncthreads();               // prev compute done (and Qs staged, 1st iter)
        // stage K rows jt*64 .. +63
#pragma unroll
        for (int r = 0; r < 2; ++r) {
            int idx = tid + r * 256;
            int row = idx >> 3, c4 = idx & 7;
            float4 v = *(const float4*)(Kt + (size_t)(jt * 64 + row) * QCH + c4 * 4);
            Ks[row][c4 * 4 + 0] = v.x; Ks[row][c4 * 4 + 1] = v.y;
            Ks[row][c4 * 4 + 2] = v.z; Ks[row][c4 * 4 + 3] = v.w;
        }
        __syncthreads();

        float e[4][4];
#pragma unroll
        for (int rr = 0; rr < 4; ++rr)
#pragma unroll
            for (int jj = 0; jj < 4; ++jj) e[rr][jj] = 0.f;

#pragma unroll
        for (int k = 0; k < 32; ++k) {
            float qv[4], kv[4];
#pragma unroll
            for (int rr = 0; rr < 4; ++rr) qv[rr] = Qs[rg * 4 + rr][k];
#pragma unroll
            for (int jj = 0; jj < 4; ++jj) kv[jj] = Ks[jg * 4 + jj][k];
#pragma unroll
            for (int rr = 0; rr < 4; ++rr)
#pragma unroll
                for (int jj = 0; jj < 4; ++jj)
                    e[rr][jj] = fmaf(qv[rr], kv[jj], e[rr][jj]);
        }

#pragma unroll
        for (int rr = 0; rr < 4; ++rr) {
            float f0 = e[rr][0] * L2E, f1 = e[rr][1] * L2E;
            float f2 = e[rr][2] * L2E, f3 = e[rr][3] * L2E;
            float m4 = fmaxf(fmaxf(f0, f1), fmaxf(f2, f3));
            float nm = fmaxf(mx[rr], m4);
            sm[rr] = sm[rr] * exp2f(mx[rr] - nm)
                   + exp2f(f0 - nm) + exp2f(f1 - nm) + exp2f(f2 - nm) + exp2f(f3 - nm);
            mx[rr] = nm;
        }
    }

    __syncthreads();
#pragma unroll
    for (int rr = 0; rr < 4; ++rr) {
        Rm[rg * 4 + rr][jg] = mx[rr];
        Rs[rg * 4 + rr][jg] = sm[rr];
    }
    __syncthreads();
    if (tid < 64) {
        float M = -1e30f;
#pragma unroll
        for (int t = 0; t < 16; ++t) M = fmaxf(M, Rm[tid][t]);
        float S = 0.f;
#pragma unroll
        for (int t = 0; t < 16; ++t) S += Rs[tid][t] * exp2f(Rm[tid][t] - M);
        a2[n0 + tid] = M + log2f(S);
    }
}

// ---------------------------------------------------------------------------
// K3: fused second pass. Per block: c-tile 128 x j-tile 64; loops n in 32s:
// recompute energy tile -> P = exp2(e*L2E - a2[n]) in LDS -> acc += V @ P.
// Epilogue: out = gamma*acc + x  (flat layout identical to reference reshape).
// ---------------------------------------------------------------------------
__global__ __launch_bounds__(256) void k_out(
    const float* __restrict__ x, const float* __restrict__ gamma,
    const float* __restrict__ ws, float* __restrict__ out)
{
    __shared__ float Ks3[64][33];   // K rows for this j-tile
    __shared__ float Qs3[32][33];   // Q rows for current n-chunk
    __shared__ float Vs[128][33];   // V[c][n] chunk
    __shared__ float Ps[32][68];    // P[n][j] tile (+pad, float4-aligned rows)
    __shared__ float a2s[32];

    const int tid = threadIdx.x;
    const int j0  = blockIdx.x * 64;
    const int c0  = blockIdx.y * 128;
    const int mi  = blockIdx.z;

    const float* Qt = ws + QT_OFF + (size_t)mi * NPIX * QCH;
    const float* Kt = ws + KT_OFF + (size_t)mi * NPIX * QCH;
    const float* V  = ws + V_OFF  + (size_t)mi * CCH * NPIX;
    const float* a2 = ws + A2_OFF + (size_t)mi * NPIX;

    // stage K rows j0..j0+63 (once per block)
#pragma unroll
    for (int r = 0; r < 2; ++r) {
        int idx = tid + r * 256;
        int row = idx >> 3, c4 = idx & 7;
        float4 v = *(const float4*)(Kt + (size_t)(j0 + row) * QCH + c4 * 4);
        Ks3[row][c4 * 4 + 0] = v.x; Ks3[row][c4 * 4 + 1] = v.y;
        Ks3[row][c4 * 4 + 2] = v.z; Ks3[row][c4 * 4 + 3] = v.w;
    }

    const int rg = tid >> 4;   // 0..15
    const int jg = tid & 15;   // 0..15

    float acc[8][4];
#pragma unroll
    for (int i = 0; i < 8; ++i)
#pragma unroll
        for (int j = 0; j < 4; ++j) acc[i][j] = 0.f;

    for (int nc = 0; nc < NPIX; nc += 32) {
        __syncthreads();   // prev iter reads done; Ks3 staged (1st iter)
        // stage Q rows nc..nc+31
        {
            int row = tid >> 3, c4 = tid & 7;
            float4 v = *(const float4*)(Qt + (size_t)(nc + row) * QCH + c4 * 4);
            Qs3[row][c4 * 4 + 0] = v.x; Qs3[row][c4 * 4 + 1] = v.y;
            Qs3[row][c4 * 4 + 2] = v.z; Qs3[row][c4 * 4 + 3] = v.w;
        }
        if (tid < 32) a2s[tid] = a2[nc + tid];
        // stage V chunk: V[c0+c][nc + 4*n4 ...]
#pragma unroll
        for (int r = 0; r < 4; ++r) {
            int idx = tid + r * 256;
            int c = idx >> 3, n4 = idx & 7;
            float4 v = *(const float4*)(V + (size_t)(c0 + c) * NPIX + nc + n4 * 4);
            Vs[c][n4 * 4 + 0] = v.x; Vs[c][n4 * 4 + 1] = v.y;
            Vs[c][n4 * 4 + 2] = v.z; Vs[c][n4 * 4 + 3] = v.w;
        }
        __syncthreads();

        // energy tile: rows rg*2 + rr (0..31), cols jg*4 + jj (0..63)
        float e[2][4];
#pragma unroll
        for (int rr = 0; rr < 2; ++rr)
#pragma unroll
            for (int jj = 0; jj < 4; ++jj) e[rr][jj] = 0.f;
#pragma unroll
        for (int k = 0; k < 32; ++k) {
            float qv[2], kv[4];
#pragma unroll
            for (int rr = 0; rr < 2; ++rr) qv[rr] = Qs3[rg * 2 + rr][k];
#pragma unroll
            for (int jj = 0; jj < 4; ++jj) kv[jj] = Ks3[jg * 4 + jj][k];
#pragma unroll
            for (int rr = 0; rr < 2; ++rr)
#pragma unroll
                for (int jj = 0; jj < 4; ++jj)
                    e[rr][jj] = fmaf(qv[rr], kv[jj], e[rr][jj]);
        }
#pragma unroll
        for (int rr = 0; rr < 2; ++rr) {
            float a = a2s[rg * 2 + rr];
#pragma unroll
            for (int jj = 0; jj < 4; ++jj)
                Ps[rg * 2 + rr][jg * 4 + jj] = exp2f(e[rr][jj] * L2E - a);
        }
        __syncthreads();

        // acc += V @ P over this n-chunk
#pragma unroll 8
        for (int nn = 0; nn < 32; ++nn) {
            float4 pv = *(const float4*)&Ps[nn][jg * 4];
            float vv[8];
#pragma unroll
            for (int i = 0; i < 8; ++i) vv[i] = Vs[rg * 8 + i][nn];
#pragma unroll
            for (int i = 0; i < 8; ++i) {
                acc[i][0] = fmaf(vv[i], pv.x, acc[i][0]);
                acc[i][1] = fmaf(vv[i], pv.y, acc[i][1]);
                acc[i][2] = fmaf(vv[i], pv.z, acc[i][2]);
                acc[i][3] = fmaf(vv[i], pv.w, acc[i][3]);
            }
        }
    }

    const float g = gamma[0];
#pragma unroll
    for (int i = 0; i < 8; ++i) {
        int c = c0 + rg * 8 + i;
        size_t base = (size_t)mi * CCH * NPIX + (size_t)c * NPIX + j0 + jg * 4;
        float4 xv = *(const float4*)(x + base);
        float4 o4 = { g * acc[i][0] + xv.x, g * acc[i][1] + xv.y,
                      g * acc[i][2] + xv.z, g * acc[i][3] + xv.w };
        *(float4*)(out + base) = o4;
    }
}

extern "C" void kernel_launch(void* const* d_in, const int* in_sizes, int n_in,
                              void* d_out, int out_size, void* d_ws, size_t ws_size,
                              hipStream_t stream)
{
    const float* x     = (const float*)d_in[0];
    const float* wq    = (const float*)d_in[1];
    const float* bq    = (const float*)d_in[2];
    const float* wk    = (const float*)d_in[3];
    const float* bk    = (const float*)d_in[4];
    const float* wv    = (const float*)d_in[5];
    const float* bv    = (const float*)d_in[6];
    const float* gamma = (const float*)d_in[7];
    float* out = (float*)d_out;
    float* ws  = (float*)d_ws;

    // K1: projections (Qt, Kt, V)
    k_proj<<<dim3(NPIX / 64, 5, MB), 256, 0, stream>>>(x, wq, bq, wk, bk, wv, bv, ws);
    // K2: softmax row statistics
    k_stats<<<dim3(NPIX / 64, MB, 1), 256, 0, stream>>>(ws);
    // K3: fused energy-recompute + softmax + V@P + residual
    k_out<<<dim3(NPIX / 64, CCH / 128, MB), 256, 0, stream>>>(x, gamma, ws, out);
}

// Round 2
// 230.186 us; speedup vs baseline: 2.5735x; 2.5735x over previous
//
#include <hip/hip_runtime.h>

#define MB    32        // B*T slices
#define CCH   256       // channels C
#define QCH   32        // q/k channels
#define NPIX  1024      // W*H
#define SLICE (CCH * NPIX)   // 262144
#define L2E   1.44269504088896340736f

typedef __bf16          bf16x8 __attribute__((ext_vector_type(8)));
typedef float           f32x4  __attribute__((ext_vector_type(4)));
typedef unsigned int    u32x4  __attribute__((ext_vector_type(4)));
typedef unsigned short  u16x4  __attribute__((ext_vector_type(4)));

__device__ __forceinline__ unsigned short f2bf(float f) {
    unsigned int u = __builtin_bit_cast(unsigned int, f);
    u += 0x7FFFu + ((u >> 16) & 1u);          // RTNE (inputs well-behaved, no NaN)
    return (unsigned short)(u >> 16);
}
__device__ __forceinline__ bf16x8 ldfrag(const unsigned short* p) {
    u32x4 u = *(const u32x4*)p;
    return __builtin_bit_cast(bf16x8, u);
}

// workspace byte offsets
#define WB_OFF 0u                 // 320*256 bf16      = 163840 B
#define A2_OFF 163840u            // 32*1024 f32       = 131072 B
#define XT_OFF 294912u            // 32*1024*256 bf16  = 16777216 B
#define QT_OFF 17072128u          // 32*1024*32 bf16   = 2097152 B
#define KT_OFF 19169280u          // 32*1024*32 bf16   = 2097152 B
#define V_OFF  21266432u          // 32*256*1024 bf16  = 16777216 B -> end ~38 MB

// ---------------------------------------------------------------------------
// K0w: convert stacked [wq;wk;wv] (320x256 f32) -> Wb bf16
// ---------------------------------------------------------------------------
__global__ __launch_bounds__(256) void k_prep_w(
    const float* __restrict__ wq, const float* __restrict__ wk,
    const float* __restrict__ wv, unsigned short* __restrict__ Wb)
{
    int i4 = (blockIdx.x * 256 + threadIdx.x) * 4;   // 80 blocks cover 81920
    int o = i4 >> 8, c = i4 & 255;
    const float* src = (o < 32) ? wq + (size_t)o * CCH + c
                     : (o < 64) ? wk + (size_t)(o - 32) * CCH + c
                                : wv + (size_t)(o - 64) * CCH + c;
    float4 v = *(const float4*)src;
    u16x4 d = { f2bf(v.x), f2bf(v.y), f2bf(v.z), f2bf(v.w) };
    *(u16x4*)(Wb + i4) = d;
}

// ---------------------------------------------------------------------------
// K0x: transpose-convert x (f32 [c][n] per slice) -> Xt bf16 [n][c]
// ---------------------------------------------------------------------------
__global__ __launch_bounds__(256) void k_prep_x(
    const float* __restrict__ x, unsigned short* __restrict__ Xt)
{
    __shared__ unsigned short Ts[64][72];
    const int t = threadIdx.x;
    const int n0 = blockIdx.x * 64, c0 = blockIdx.y * 64, mi = blockIdx.z;
    const float* xp = x + (size_t)mi * SLICE;
    unsigned short* Xp = Xt + (size_t)mi * SLICE;
#pragma unroll
    for (int r = 0; r < 4; ++r) {
        int cl = (t >> 4) + r * 16;
        int nl = (t & 15) * 4;
        float4 v = *(const float4*)(xp + (size_t)(c0 + cl) * NPIX + n0 + nl);
        Ts[nl + 0][cl] = f2bf(v.x); Ts[nl + 1][cl] = f2bf(v.y);
        Ts[nl + 2][cl] = f2bf(v.z); Ts[nl + 3][cl] = f2bf(v.w);
    }
    __syncthreads();
#pragma unroll
    for (int r = 0; r < 4; ++r) {
        int nl = (t >> 4) + r * 16;
        int cl = (t & 15) * 4;
        u16x4 d = *(const u16x4*)&Ts[nl][cl];
        *(u16x4*)(Xp + (size_t)(n0 + nl) * CCH + c0 + cl) = d;
    }
}

// ---------------------------------------------------------------------------
// K1: MFMA projections. O(320x1024) = Wb @ Xt^T per slice.
// Wave: o-tile 16 x n-tile 64 (4 sub-tiles). A=Wb rows, B=Xt rows.
// Epilogue: o<32 -> Qt[n][o] bf16 *L2E + bq; o<64 -> Kt[n][o] + bk; else V[c][n] + bv.
// ---------------------------------------------------------------------------
__global__ __launch_bounds__(256) void k_proj(
    const unsigned short* __restrict__ Wb, const unsigned short* __restrict__ Xt,
    const float* __restrict__ bq, const float* __restrict__ bk,
    const float* __restrict__ bv,
    unsigned short* __restrict__ Qt, unsigned short* __restrict__ Kt,
    unsigned short* __restrict__ V)
{
    const int t = threadIdx.x, lane = t & 63, w = t >> 6;
    const int lj = lane & 15, q = lane >> 4;
    const int n0 = blockIdx.x * 64;
    const int o16 = blockIdx.y * 64 + w * 16;
    const int mi = blockIdx.z;
    const unsigned short* Xp = Xt + (size_t)mi * SLICE;

    f32x4 acc[4];
#pragma unroll
    for (int b = 0; b < 4; ++b) acc[b] = (f32x4){0.f, 0.f, 0.f, 0.f};

#pragma unroll
    for (int kc = 0; kc < CCH; kc += 32) {
        bf16x8 a = ldfrag(Wb + (size_t)(o16 + lj) * CCH + kc + q * 8);
#pragma unroll
        for (int b = 0; b < 4; ++b) {
            bf16x8 xb = ldfrag(Xp + (size_t)(n0 + b * 16 + lj) * CCH + kc + q * 8);
            acc[b] = __builtin_amdgcn_mfma_f32_16x16x32_bf16(a, xb, acc[b], 0, 0, 0);
        }
    }

    const int ob = o16 + 4 * q;        // this lane's 4 output rows: ob..ob+3
    if (o16 < 32) {                    // Q -> Qt[n][o], pre-scaled by log2(e)
        unsigned short* Qp = Qt + (size_t)mi * NPIX * QCH;
        float b0 = bq[ob], b1 = bq[ob + 1], b2 = bq[ob + 2], b3 = bq[ob + 3];
#pragma unroll
        for (int b = 0; b < 4; ++b) {
            int n = n0 + b * 16 + lj;
            u16x4 d = { f2bf((acc[b][0] + b0) * L2E), f2bf((acc[b][1] + b1) * L2E),
                        f2bf((acc[b][2] + b2) * L2E), f2bf((acc[b][3] + b3) * L2E) };
            *(u16x4*)(Qp + (size_t)n * QCH + ob) = d;
        }
    } else if (o16 < 64) {             // K -> Kt[n][o]
        unsigned short* Kp = Kt + (size_t)mi * NPIX * QCH;
        int o2 = ob - 32;
        float b0 = bk[o2], b1 = bk[o2 + 1], b2 = bk[o2 + 2], b3 = bk[o2 + 3];
#pragma unroll
        for (int b = 0; b < 4; ++b) {
            int n = n0 + b * 16 + lj;
            u16x4 d = { f2bf(acc[b][0] + b0), f2bf(acc[b][1] + b1),
                        f2bf(acc[b][2] + b2), f2bf(acc[b][3] + b3) };
            *(u16x4*)(Kp + (size_t)n * QCH + o2) = d;
        }
    } else {                           // V -> V[c][n]
        unsigned short* Vp = V + (size_t)mi * SLICE;
        int cb = ob - 64;
        float bb[4] = { bv[cb], bv[cb + 1], bv[cb + 2], bv[cb + 3] };
#pragma unroll
        for (int b = 0; b < 4; ++b) {
            int n = n0 + b * 16 + lj;
#pragma unroll
            for (int r = 0; r < 4; ++r)
                Vp[(size_t)(cb + r) * NPIX + n] = f2bf(acc[b][r] + bb[r]);
        }
    }
}

// ---------------------------------------------------------------------------
// K2: softmax row stats via the SAME mfma tiles K3 uses (bitwise-consistent E).
// Wave: 16 energy rows; loop 64 j-chunks; online (m,s) in exp2 domain;
// butterfly over the 16 column-lanes; a2[n] = m + log2(s).
// ---------------------------------------------------------------------------
__global__ __launch_bounds__(256) void k_stats(
    const unsigned short* __restrict__ Qt, const unsigned short* __restrict__ Kt,
    float* __restrict__ a2f)
{
    const int t = threadIdx.x, lane = t & 63, w = t >> 6;
    const int lj = lane & 15, q = lane >> 4;
    const int n16 = blockIdx.x * 64 + w * 16;
    const int mi = blockIdx.y;
    const unsigned short* Qp = Qt + (size_t)mi * NPIX * QCH;
    const unsigned short* Kp = Kt + (size_t)mi * NPIX * QCH;

    bf16x8 qa = ldfrag(Qp + (size_t)(n16 + lj) * QCH + q * 8);

    float m[4] = { -3e38f, -3e38f, -3e38f, -3e38f };
    float s[4] = { 0.f, 0.f, 0.f, 0.f };

#pragma unroll 4
    for (int jc = 0; jc < NPIX; jc += 16) {
        bf16x8 kb = ldfrag(Kp + (size_t)(jc + lj) * QCH + q * 8);
        f32x4 z = (f32x4){0.f, 0.f, 0.f, 0.f};
        f32x4 e = __builtin_amdgcn_mfma_f32_16x16x32_bf16(qa, kb, z, 0, 0, 0);
#pragma unroll
        for (int r = 0; r < 4; ++r) {
            float nm = fmaxf(m[r], e[r]);
            s[r] = s[r] * exp2f(m[r] - nm) + exp2f(e[r] - nm);
            m[r] = nm;
        }
    }
#pragma unroll
    for (int msk = 1; msk <= 8; msk <<= 1) {
#pragma unroll
        for (int r = 0; r < 4; ++r) {
            float om = __shfl_xor(m[r], msk, 64);
            float os = __shfl_xor(s[r], msk, 64);
            float nm = fmaxf(m[r], om);
            s[r] = s[r] * exp2f(m[r] - nm) + os * exp2f(om - nm);
            m[r] = nm;
        }
    }
    if (lj == 0) {
        float* ap = a2f + (size_t)mi * NPIX;
#pragma unroll
        for (int r = 0; r < 4; ++r)
            ap[n16 + 4 * q + r] = m[r] + log2f(s[r]);
    }
}

// ---------------------------------------------------------------------------
// K3: fused second pass. Block = j-tile 64 (16 j per wave) x all 256 channels.
// Loop n in 32s: E (2 mfma) -> P=exp2(E-a2) -> LDS (padded) -> 16 V.P mfma.
// Epilogue: out = gamma*acc + x.
// ---------------------------------------------------------------------------
__global__ __launch_bounds__(256) void k_attn_out(
    const float* __restrict__ x, const float* __restrict__ gamma,
    const unsigned short* __restrict__ Qt, const unsigned short* __restrict__ Kt,
    const unsigned short* __restrict__ V, const float* __restrict__ a2f,
    float* __restrict__ out)
{
    __shared__ unsigned short Vs[256 * 40];     // rows padded 32->40 (80 B): <=2-way banks
    __shared__ unsigned short Ps[4][16][40];    // per-wave P tile [j][n], 80 B rows

    const int t = threadIdx.x, lane = t & 63, w = t >> 6;
    const int lj = lane & 15, q = lane >> 4;
    const int j0 = blockIdx.x * 64, mi = blockIdx.y;
    const int j16 = j0 + w * 16;

    const unsigned short* Qp = Qt + (size_t)mi * NPIX * QCH;
    const unsigned short* Kp = Kt + (size_t)mi * NPIX * QCH;
    const unsigned short* Vp = V + (size_t)mi * SLICE;
    const float* ap = a2f + (size_t)mi * NPIX;

    bf16x8 kb = ldfrag(Kp + (size_t)(j16 + lj) * QCH + q * 8);   // fixed per wave

    f32x4 acc[16];
#pragma unroll
    for (int ct = 0; ct < 16; ++ct) acc[ct] = (f32x4){0.f, 0.f, 0.f, 0.f};

    for (int nc = 0; nc < NPIX; nc += 32) {
        __syncthreads();               // prev chunk's Vs reads done
        // stage V[0..256][nc..nc+32] -> Vs (padded rows)
#pragma unroll
        for (int ri = 0; ri < 4; ++ri) {
            int idx = ri * 256 + t;
            int c = idx >> 2, s2 = idx & 3;
            u32x4 d = *(const u32x4*)(Vp + (size_t)c * NPIX + nc + s2 * 8);
            *(u32x4*)&Vs[c * 40 + s2 * 8] = d;
        }
        __syncthreads();

        // E phase: two 16x16 tiles -> P bf16 into Ps (wave-local)
#pragma unroll
        for (int sub = 0; sub < 2; ++sub) {
            int nr = nc + sub * 16;
            bf16x8 qa = ldfrag(Qp + (size_t)(nr + lj) * QCH + q * 8);
            f32x4 z = (f32x4){0.f, 0.f, 0.f, 0.f};
            f32x4 e = __builtin_amdgcn_mfma_f32_16x16x32_bf16(qa, kb, z, 0, 0, 0);
            f32x4 a4 = *(const f32x4*)(ap + nr + 4 * q);
            u16x4 pv = { f2bf(exp2f(e[0] - a4[0])), f2bf(exp2f(e[1] - a4[1])),
                         f2bf(exp2f(e[2] - a4[2])), f2bf(exp2f(e[3] - a4[3])) };
            *(u16x4*)&Ps[w][lj][sub * 16 + 4 * q] = pv;
        }
        bf16x8 pf = ldfrag(&Ps[w][lj][q * 8]);   // B operand: P[n=q*8+i][j=lj]

        // O accumulation: 16 c-tiles
#pragma unroll
        for (int ct = 0; ct < 16; ++ct) {
            bf16x8 vf = ldfrag(&Vs[(ct * 16 + lj) * 40 + q * 8]);
            acc[ct] = __builtin_amdgcn_mfma_f32_16x16x32_bf16(vf, pf, acc[ct], 0, 0, 0);
        }
    }

    const float g = gamma[0];
    const size_t obase = (size_t)mi * SLICE;
#pragma unroll
    for (int ct = 0; ct < 16; ++ct) {
#pragma unroll
        for (int r = 0; r < 4; ++r) {
            int c = ct * 16 + 4 * q + r;
            size_t off = obase + (size_t)c * NPIX + j16 + lj;
            out[off] = g * acc[ct][r] + x[off];
        }
    }
}

extern "C" void kernel_launch(void* const* d_in, const int* in_sizes, int n_in,
                              void* d_out, int out_size, void* d_ws, size_t ws_size,
                              hipStream_t stream)
{
    const float* x     = (const float*)d_in[0];
    const float* wq    = (const float*)d_in[1];
    const float* bq    = (const float*)d_in[2];
    const float* wk    = (const float*)d_in[3];
    const float* bk    = (const float*)d_in[4];
    const float* wv    = (const float*)d_in[5];
    const float* bv    = (const float*)d_in[6];
    const float* gamma = (const float*)d_in[7];
    float* out = (float*)d_out;

    char* wsb = (char*)d_ws;
    unsigned short* Wb = (unsigned short*)(wsb + WB_OFF);
    float*          a2 = (float*)(wsb + A2_OFF);
    unsigned short* Xt = (unsigned short*)(wsb + XT_OFF);
    unsigned short* Qt = (unsigned short*)(wsb + QT_OFF);
    unsigned short* Kt = (unsigned short*)(wsb + KT_OFF);
    unsigned short* V  = (unsigned short*)(wsb + V_OFF);

    k_prep_w<<<80, 256, 0, stream>>>(wq, wk, wv, Wb);
    k_prep_x<<<dim3(NPIX / 64, CCH / 64, MB), 256, 0, stream>>>(x, Xt);
    k_proj<<<dim3(NPIX / 64, 5, MB), 256, 0, stream>>>(Wb, Xt, bq, bk, bv, Qt, Kt, V);
    k_stats<<<dim3(NPIX / 64, MB), 256, 0, stream>>>(Qt, Kt, a2);
    k_attn_out<<<dim3(NPIX / 64, MB), 256, 0, stream>>>(x, gamma, Qt, Kt, V, a2, out);
}